// Round 1
// baseline (401.943 us; speedup 1.0000x reference)
//
#include <hip/hip_runtime.h>

#define B_ 64
#define C_ 256
#define TV_ 1600
#define V_ 25
#define H_ 8

typedef __attribute__((ext_vector_type(2))) int   intx2;
typedef __attribute__((ext_vector_type(4))) int   intx4;
typedef __attribute__((ext_vector_type(4))) float floatx4;
typedef __attribute__((ext_vector_type(8))) short short8;

union FragCast { intx4 i; short8 s; };

__device__ __forceinline__ unsigned short f2bf(float f) {
    union { float f; unsigned u; } c; c.f = f;
    unsigned u = c.u;
    u += 0x7fffu + ((u >> 16) & 1u);   // RNE (no NaN inputs in this problem)
    return (unsigned short)(u >> 16);
}
__device__ __forceinline__ float bf2f(unsigned short s) {
    union { unsigned u; float f; } c; c.u = ((unsigned)s) << 16;
    return c.f;
}
__device__ __forceinline__ int pk_bf2(float a, float b) {
    return (int)((unsigned)f2bf(a) | ((unsigned)f2bf(b) << 16));
}

// ---------------- K1: x_patch (B,C,1600) fp32 -> XNC (B,1600,256) bf16 ----------------
__global__ __launch_bounds__(256) void k1_trans(const float* __restrict__ xp,
                                                unsigned short* __restrict__ XNC) {
    __shared__ float xs[128 * 68];   // 128 c rows x 64 n, pad 68 to spread banks
    const int blk = blockIdx.x;
    const int b = blk / 25, nb = blk - b * 25;
    const int n0 = nb * 64;
    const int t = threadIdx.x;
    const int cl = t & 127, nh = (t >> 7) * 32;
    const int n = t & 63, cg = t >> 6;
    for (int p = 0; p < 2; p++) {
        const float* src = xp + ((size_t)(b * C_ + p * 128 + cl)) * TV_ + n0 + nh;
        floatx4 v[8];
        #pragma unroll
        for (int j = 0; j < 8; j++) v[j] = *(const floatx4*)(src + 4 * j);
        if (p) __syncthreads();
        #pragma unroll
        for (int j = 0; j < 8; j++) *(floatx4*)&xs[cl * 68 + nh + 4 * j] = v[j];
        __syncthreads();
        unsigned short* dst = XNC + ((size_t)(b * TV_ + n0 + n)) * C_ + p * 128 + cg * 32;
        #pragma unroll
        for (int j8 = 0; j8 < 4; j8++) {
            const int cb = cg * 32 + j8 * 8;
            intx4 w;
            w[0] = pk_bf2(xs[(cb + 0) * 68 + n], xs[(cb + 1) * 68 + n]);
            w[1] = pk_bf2(xs[(cb + 2) * 68 + n], xs[(cb + 3) * 68 + n]);
            w[2] = pk_bf2(xs[(cb + 4) * 68 + n], xs[(cb + 5) * 68 + n]);
            w[3] = pk_bf2(xs[(cb + 6) * 68 + n], xs[(cb + 7) * 68 + n]);
            *(intx4*)(dst + j8 * 8) = w;
        }
        if (!p) __syncthreads();
    }
}

// ---------------- K0: Qt[b,h,32,256] bf16 = temp[h]/sqrt(32)*log2e * (xc @ qw_h^T) @ kw_h ----
__global__ __launch_bounds__(256) void k0_qtilde(const float* __restrict__ xcls,
        const float* __restrict__ qw, const float* __restrict__ kw,
        const float* __restrict__ temp, unsigned short* __restrict__ QT) {
    __shared__ float xcs[C_ * 26];    // [c][q] pad 26
    __shared__ float qh[25 * 33];     // [q][d] pad 33
    __shared__ float kws[32 * 264];   // [d][c] pad 264
    const int blk = blockIdx.x;
    const int b = blk >> 3, h = blk & 7;
    const int t = threadIdx.x;
    {
        const float* src = xcls + ((size_t)(b * C_ + t)) * V_;
        #pragma unroll
        for (int q = 0; q < V_; q++) xcs[t * 26 + q] = src[q];
    }
    {
        const int d = t >> 3, c0 = (t & 7) * 32;
        const float* src = kw + (size_t)(h * 32 + d) * C_ + c0;
        #pragma unroll
        for (int j = 0; j < 32; j++) kws[d * 264 + c0 + j] = src[j];
    }
    __syncthreads();
    for (int idx = t; idx < 800; idx += 256) {
        const int q = idx >> 5, d = idx & 31;
        const float* qwr = qw + (size_t)(h * 32 + d) * C_;
        float acc = 0.f;
        for (int c = 0; c < C_; c++) acc += xcs[c * 26 + q] * qwr[c];
        qh[q * 33 + d] = acc;
    }
    __syncthreads();
    const float scale = temp[h] * 0.17677669529663689f * 1.4426950408889634f;
    const int qp = t & 31, cg = t >> 5;
    const int c0 = cg * 32;
    float acc[32];
    #pragma unroll
    for (int j = 0; j < 32; j++) acc[j] = 0.f;
    if (qp < 25) {
        for (int d = 0; d < 32; d++) {
            const float a = qh[qp * 33 + d];
            const float* kr = &kws[d * 264 + c0];
            #pragma unroll
            for (int j = 0; j < 32; j++) acc[j] += a * kr[j];
        }
    }
    unsigned short* dst = QT + ((size_t)((b * H_ + h) * 32 + qp)) * C_ + c0;
    #pragma unroll
    for (int j8 = 0; j8 < 4; j8++) {
        intx4 w;
        w[0] = pk_bf2(scale * acc[j8 * 8 + 0], scale * acc[j8 * 8 + 1]);
        w[1] = pk_bf2(scale * acc[j8 * 8 + 2], scale * acc[j8 * 8 + 3]);
        w[2] = pk_bf2(scale * acc[j8 * 8 + 4], scale * acc[j8 * 8 + 5]);
        w[3] = pk_bf2(scale * acc[j8 * 8 + 6], scale * acc[j8 * 8 + 7]);
        *(intx4*)(dst + j8 * 8) = w;
    }
}

// ---------------- K2: fused attention per (b,h): S=Qt@Xnc^T, P=exp2(S), W=P@Xcn, out=(W/l)@vw_h^T
__global__ __launch_bounds__(256) void k2_attn(const float* __restrict__ xp,
        const unsigned short* __restrict__ XNC, const unsigned short* __restrict__ QT,
        const float* __restrict__ vw, float* __restrict__ OA) {
    __shared__ unsigned short P_s[2][32 * 72];   // P tile, rows padded to 72 bf16
    __shared__ float psum_s[4][32];
    __shared__ float rl_s[32];
    __shared__ unsigned short Wl[32 * 264];      // epilogue W bf16
    __shared__ unsigned short vws[32 * 264];     // epilogue v_w head slice bf16

    const int blk = blockIdx.x;
    // XCD swizzle: the 8 heads of one batch land on one XCD (blk%8 = b/8)
    const int b = (blk & 7) * 8 + ((blk >> 3) & 7);
    const int h = blk >> 6;
    const int tid = threadIdx.x;
    const int wv = tid >> 6, lane = tid & 63;
    const int quad = lane >> 4, l16 = lane & 15;

    short8 qf[2][8];
    {
        const unsigned short* qb = QT + ((size_t)(b * H_ + h)) * 32 * C_;
        #pragma unroll
        for (int mt = 0; mt < 2; mt++)
            #pragma unroll
            for (int ks = 0; ks < 8; ks++)
                qf[mt][ks] = *(const short8*)(qb + (mt * 16 + l16) * C_ + ks * 32 + quad * 8);
    }
    floatx4 wacc[2][4];
    #pragma unroll
    for (int mt = 0; mt < 2; mt++)
        #pragma unroll
        for (int cs = 0; cs < 4; cs++) wacc[mt][cs] = (floatx4){0.f, 0.f, 0.f, 0.f};
    float lsum[8];
    #pragma unroll
    for (int i = 0; i < 8; i++) lsum[i] = 0.f;

    const unsigned short* xnc_b = XNC + (size_t)b * TV_ * C_;
    const float* xp_b = xp + (size_t)b * C_ * TV_;

    for (int ti = 0; ti < 25; ti++) {
        const int n0 = ti * 64;
        const int par = ti & 1;
        floatx4 sc0 = {0.f, 0.f, 0.f, 0.f}, sc1 = {0.f, 0.f, 0.f, 0.f};
        {
            const unsigned short* xr = xnc_b + (size_t)(n0 + wv * 16 + l16) * C_ + quad * 8;
            #pragma unroll
            for (int ks = 0; ks < 8; ks++) {
                const short8 bfv = *(const short8*)(xr + ks * 32);
                sc0 = __builtin_amdgcn_mfma_f32_16x16x32_bf16(qf[0][ks], bfv, sc0, 0, 0, 0);
                sc1 = __builtin_amdgcn_mfma_f32_16x16x32_bf16(qf[1][ks], bfv, sc1, 0, 0, 0);
            }
        }
        {   // no max-subtraction needed: |S_log2| << 1, exp2 cannot overflow
            const int colp = wv * 16 + l16;
            #pragma unroll
            for (int r = 0; r < 4; r++) {
                const float p0 = __builtin_amdgcn_exp2f(sc0[r]);
                const float p1 = __builtin_amdgcn_exp2f(sc1[r]);
                lsum[r] += p0;
                lsum[4 + r] += p1;
                P_s[par][(quad * 4 + r) * 72 + colp] = f2bf(p0);
                P_s[par][(16 + quad * 4 + r) * 72 + colp] = f2bf(p1);
            }
        }
        __syncthreads();
        #pragma unroll
        for (int ks = 0; ks < 2; ks++) {
            const short8 a0 = *(const short8*)&P_s[par][l16 * 72 + ks * 32 + quad * 8];
            const short8 a1 = *(const short8*)&P_s[par][(16 + l16) * 72 + ks * 32 + quad * 8];
            #pragma unroll
            for (int cs = 0; cs < 4; cs++) {
                const int c = wv * 64 + cs * 16 + l16;
                const float* xrow = xp_b + (size_t)c * TV_ + n0 + ks * 32 + quad * 8;
                const floatx4 f0 = *(const floatx4*)(xrow);
                const floatx4 f1 = *(const floatx4*)(xrow + 4);
                FragCast bc;
                bc.i[0] = pk_bf2(f0[0], f0[1]);
                bc.i[1] = pk_bf2(f0[2], f0[3]);
                bc.i[2] = pk_bf2(f1[0], f1[1]);
                bc.i[3] = pk_bf2(f1[2], f1[3]);
                wacc[0][cs] = __builtin_amdgcn_mfma_f32_16x16x32_bf16(a0, bc.s, wacc[0][cs], 0, 0, 0);
                wacc[1][cs] = __builtin_amdgcn_mfma_f32_16x16x32_bf16(a1, bc.s, wacc[1][cs], 0, 0, 0);
            }
        }
    }
    // ---- epilogue ----
    #pragma unroll
    for (int i = 0; i < 8; i++) {
        float v = lsum[i];
        #pragma unroll
        for (int off = 1; off < 16; off <<= 1) v += __shfl_xor(v, off, 64);
        lsum[i] = v;
    }
    if (l16 == 0) {
        #pragma unroll
        for (int mt = 0; mt < 2; mt++)
            #pragma unroll
            for (int r = 0; r < 4; r++)
                psum_s[wv][mt * 16 + quad * 4 + r] = lsum[mt * 4 + r];
    }
    #pragma unroll
    for (int mt = 0; mt < 2; mt++)
        #pragma unroll
        for (int cs = 0; cs < 4; cs++)
            #pragma unroll
            for (int r = 0; r < 4; r++)
                Wl[(mt * 16 + quad * 4 + r) * 264 + wv * 64 + cs * 16 + l16] = f2bf(wacc[mt][cs][r]);
    {
        const int d = tid >> 3, c0 = (tid & 7) * 32;
        const float* src = vw + (size_t)(h * 32 + d) * C_ + c0;
        #pragma unroll
        for (int j = 0; j < 16; j++)
            *(int*)&vws[d * 264 + c0 + 2 * j] = pk_bf2(src[2 * j], src[2 * j + 1]);
    }
    __syncthreads();
    if (tid < 32) {
        const float l = psum_s[0][tid] + psum_s[1][tid] + psum_s[2][tid] + psum_s[3][tid];
        rl_s[tid] = 1.0f / l;
    }
    __syncthreads();
    {
        const int mt = wv & 1, ds = wv >> 1;
        floatx4 oc = {0.f, 0.f, 0.f, 0.f};
        #pragma unroll
        for (int ks = 0; ks < 8; ks++) {
            const short8 a  = *(const short8*)&Wl[(mt * 16 + l16) * 264 + ks * 32 + quad * 8];
            const short8 bv = *(const short8*)&vws[(ds * 16 + l16) * 264 + ks * 32 + quad * 8];
            oc = __builtin_amdgcn_mfma_f32_16x16x32_bf16(a, bv, oc, 0, 0, 0);
        }
        #pragma unroll
        for (int r = 0; r < 4; r++) {
            const int q = mt * 16 + quad * 4 + r;
            if (q < 25)
                OA[((size_t)(b * 25 + q)) * C_ + h * 32 + ds * 16 + l16] = oc[r] * rl_s[q];
        }
    }
}

// ---------------- K3: y[b,i,q] = proj_b[i] + sum_j proj_w[i,j]*OA[b,q,j] ----------------
__global__ __launch_bounds__(256) void k3_proj(const float* __restrict__ OA,
        const float* __restrict__ pw, const float* __restrict__ pb,
        float* __restrict__ y) {
    __shared__ unsigned short pws[64 * 260];   // proj_w rows i0..i0+63, bf16, pad 260
    __shared__ unsigned short outs[28 * 264];  // OA[b] bf16, rows padded (25..27 garbage, never stored)
    __shared__ float ys[1600];
    const int blk = blockIdx.x;
    const int b = blk >> 2, i0 = (blk & 3) * 64;
    const int t = threadIdx.x;
    {
        const int ilw = t >> 2, seg = t & 3;
        const float* src = pw + (size_t)(i0 + ilw) * C_ + seg * 64;
        #pragma unroll
        for (int j = 0; j < 32; j++)
            *(int*)&pws[ilw * 260 + seg * 64 + 2 * j] = pk_bf2(src[2 * j], src[2 * j + 1]);
    }
    {
        const float* src = OA + (size_t)b * (V_ * C_);
        for (int k = t; k < V_ * C_; k += 256) {
            const int q = k >> 8, j = k & 255;
            outs[q * 264 + j] = f2bf(src[k]);
        }
    }
    __syncthreads();
    const int il = t >> 2, qg = t & 3;
    const float bias = pb[i0 + il];
    float acc[7];
    #pragma unroll
    for (int jj = 0; jj < 7; jj++) acc[jj] = 0.f;
    for (int jv = 0; jv < 64; jv++) {
        const intx2 wp = *(const intx2*)&pws[il * 260 + 4 * jv];
        const float w0 = bf2f((unsigned short)(wp[0] & 0xffff));
        const float w1 = bf2f((unsigned short)((unsigned)wp[0] >> 16));
        const float w2 = bf2f((unsigned short)(wp[1] & 0xffff));
        const float w3 = bf2f((unsigned short)((unsigned)wp[1] >> 16));
        #pragma unroll
        for (int jj = 0; jj < 7; jj++) {
            const int q = qg + 4 * jj;
            const intx2 op = *(const intx2*)&outs[q * 264 + 4 * jv];
            const float o0 = bf2f((unsigned short)(op[0] & 0xffff));
            const float o1 = bf2f((unsigned short)((unsigned)op[0] >> 16));
            const float o2 = bf2f((unsigned short)(op[1] & 0xffff));
            const float o3 = bf2f((unsigned short)((unsigned)op[1] >> 16));
            acc[jj] += w0 * o0 + w1 * o1 + w2 * o2 + w3 * o3;
        }
    }
    #pragma unroll
    for (int jj = 0; jj < 7; jj++) {
        const int q = qg + 4 * jj;
        if (q < 25) ys[il * 25 + q] = bias + acc[jj];
    }
    __syncthreads();
    float* dst = y + (size_t)b * (C_ * V_) + i0 * 25;
    for (int k = t; k < 1600; k += 256) dst[k] = ys[k];
}

extern "C" void kernel_launch(void* const* d_in, const int* in_sizes, int n_in,
                              void* d_out, int out_size, void* d_ws, size_t ws_size,
                              hipStream_t stream) {
    const float* xcls = (const float*)d_in[0];
    const float* xp   = (const float*)d_in[1];
    const float* qw   = (const float*)d_in[2];
    const float* kw   = (const float*)d_in[3];
    const float* vw   = (const float*)d_in[4];
    const float* temp = (const float*)d_in[5];
    const float* pw   = (const float*)d_in[6];
    const float* pb   = (const float*)d_in[7];
    float* y = (float*)d_out;

    // ws layout: XNC bf16 52,428,800 | QT bf16 8,388,608 | OA f32 1,638,400  (= 62,455,808 B)
    if (ws_size < (size_t)62455808) return;  // sentinel: ws too small -> output stays zero
    char* ws = (char*)d_ws;
    unsigned short* XNC = (unsigned short*)ws;
    unsigned short* QT  = (unsigned short*)(ws + 52428800);
    float*          OA  = (float*)(ws + 52428800 + 8388608);

    hipLaunchKernelGGL(k1_trans,  dim3(1600), dim3(256), 0, stream, xp, XNC);
    hipLaunchKernelGGL(k0_qtilde, dim3(512),  dim3(256), 0, stream, xcls, qw, kw, temp, QT);
    hipLaunchKernelGGL(k2_attn,   dim3(512),  dim3(256), 0, stream, xp, XNC, QT, vw, OA);
    hipLaunchKernelGGL(k3_proj,   dim3(256),  dim3(256), 0, stream, OA, pw, pb, y);
}

// Round 2
// 352.053 us; speedup vs baseline: 1.1417x; 1.1417x over previous
//
#include <hip/hip_runtime.h>

#define B_ 64
#define C_ 256
#define TV_ 1600
#define V_ 25
#define H_ 8

typedef __attribute__((ext_vector_type(2))) int   intx2;
typedef __attribute__((ext_vector_type(4))) int   intx4;
typedef __attribute__((ext_vector_type(4))) float floatx4;
typedef __attribute__((ext_vector_type(8))) short short8;

__device__ __forceinline__ unsigned short f2bf(float f) {
    union { float f; unsigned u; } c; c.f = f;
    unsigned u = c.u;
    u += 0x7fffu + ((u >> 16) & 1u);   // RNE (no NaN inputs in this problem)
    return (unsigned short)(u >> 16);
}
__device__ __forceinline__ float bf2f(unsigned short s) {
    union { unsigned u; float f; } c; c.u = ((unsigned)s) << 16;
    return c.f;
}
__device__ __forceinline__ int pk_bf2(float a, float b) {
    return (int)((unsigned)f2bf(a) | ((unsigned)f2bf(b) << 16));
}

// ---------------- Kz: zero the OA32+L accumulator region ----------------
__global__ __launch_bounds__(256) void kz_zero(float* __restrict__ p) {
    const int i = blockIdx.x * 256 + threadIdx.x;   // 528*256 = 135168 float4 = 2162688 B
    ((floatx4*)p)[i] = (floatx4){0.f, 0.f, 0.f, 0.f};
}

// ---------------- K1: x_patch (B,C,1600) fp32 -> XNC (B,1600,256) bf16 ----------------
__global__ __launch_bounds__(256) void k1_trans(const float* __restrict__ xp,
                                                unsigned short* __restrict__ XNC) {
    __shared__ float xs[128 * 68];
    const int blk = blockIdx.x;
    const int b = blk / 25, nb = blk - b * 25;
    const int n0 = nb * 64;
    const int t = threadIdx.x;
    const int cl = t & 127, nh = (t >> 7) * 32;
    const int n = t & 63, cg = t >> 6;
    for (int p = 0; p < 2; p++) {
        const float* src = xp + ((size_t)(b * C_ + p * 128 + cl)) * TV_ + n0 + nh;
        floatx4 v[8];
        #pragma unroll
        for (int j = 0; j < 8; j++) v[j] = *(const floatx4*)(src + 4 * j);
        if (p) __syncthreads();
        #pragma unroll
        for (int j = 0; j < 8; j++) *(floatx4*)&xs[cl * 68 + nh + 4 * j] = v[j];
        __syncthreads();
        unsigned short* dst = XNC + ((size_t)(b * TV_ + n0 + n)) * C_ + p * 128 + cg * 32;
        #pragma unroll
        for (int j8 = 0; j8 < 4; j8++) {
            const int cb = cg * 32 + j8 * 8;
            intx4 w;
            w[0] = pk_bf2(xs[(cb + 0) * 68 + n], xs[(cb + 1) * 68 + n]);
            w[1] = pk_bf2(xs[(cb + 2) * 68 + n], xs[(cb + 3) * 68 + n]);
            w[2] = pk_bf2(xs[(cb + 4) * 68 + n], xs[(cb + 5) * 68 + n]);
            w[3] = pk_bf2(xs[(cb + 6) * 68 + n], xs[(cb + 7) * 68 + n]);
            *(intx4*)(dst + j8 * 8) = w;
        }
        if (!p) __syncthreads();
    }
}

// ---------------- K0: Qt[b,h,25,256] bf16 = temp[h]/sqrt(32)*log2e * (xc @ qw_h^T) @ kw_h ----
__global__ __launch_bounds__(256) void k0_qtilde(const float* __restrict__ xcls,
        const float* __restrict__ qw, const float* __restrict__ kw,
        const float* __restrict__ temp, unsigned short* __restrict__ QT) {
    __shared__ float xcs[C_ * 26];
    __shared__ float qh[25 * 33];
    __shared__ float kws[32 * 264];
    const int blk = blockIdx.x;
    const int b = blk >> 3, h = blk & 7;
    const int t = threadIdx.x;
    {
        const float* src = xcls + ((size_t)(b * C_ + t)) * V_;
        #pragma unroll
        for (int q = 0; q < V_; q++) xcs[t * 26 + q] = src[q];
    }
    {
        const int d = t >> 3, c0 = (t & 7) * 32;
        const float* src = kw + (size_t)(h * 32 + d) * C_ + c0;
        #pragma unroll
        for (int j = 0; j < 32; j++) kws[d * 264 + c0 + j] = src[j];
    }
    __syncthreads();
    for (int idx = t; idx < 800; idx += 256) {
        const int q = idx >> 5, d = idx & 31;
        const float* qwr = qw + (size_t)(h * 32 + d) * C_;
        float acc = 0.f;
        for (int c = 0; c < C_; c++) acc += xcs[c * 26 + q] * qwr[c];
        qh[q * 33 + d] = acc;
    }
    __syncthreads();
    const float scale = temp[h] * 0.17677669529663689f * 1.4426950408889634f;
    const int qp = t & 31, cg = t >> 5;
    const int c0 = cg * 32;
    if (qp < 25) {
        float acc[32];
        #pragma unroll
        for (int j = 0; j < 32; j++) acc[j] = 0.f;
        for (int d = 0; d < 32; d++) {
            const float a = qh[qp * 33 + d];
            const float* kr = &kws[d * 264 + c0];
            #pragma unroll
            for (int j = 0; j < 32; j++) acc[j] += a * kr[j];
        }
        unsigned short* dst = QT + ((size_t)((b * H_ + h) * 25 + qp)) * C_ + c0;
        #pragma unroll
        for (int j8 = 0; j8 < 4; j8++) {
            intx4 w;
            w[0] = pk_bf2(scale * acc[j8 * 8 + 0], scale * acc[j8 * 8 + 1]);
            w[1] = pk_bf2(scale * acc[j8 * 8 + 2], scale * acc[j8 * 8 + 3]);
            w[2] = pk_bf2(scale * acc[j8 * 8 + 4], scale * acc[j8 * 8 + 5]);
            w[3] = pk_bf2(scale * acc[j8 * 8 + 6], scale * acc[j8 * 8 + 7]);
            *(intx4*)(dst + j8 * 8) = w;
        }
    }
}

// ---------------- K2: per (b,h,s): S=Qt@Xnc^T, P=exp2(S), V=Xnc@vw_h^T (fused), PV -> atomics
__global__ __launch_bounds__(256, 2) void k2_attn(
        const unsigned short* __restrict__ XNC, const unsigned short* __restrict__ QT,
        const float* __restrict__ vw, float* __restrict__ OA32, float* __restrict__ Lsum) {
    __shared__ unsigned short P_s[2][32 * 72];
    __shared__ unsigned short V_s[2][32 * 72];
    __shared__ unsigned short vws[32 * 264];

    const int blk = blockIdx.x;
    // blk = h*320 + b*5 + s: the 8 h-twins of one (b,s) slice share blk%8 -> same XCD
    const int h = blk / 320;
    const int rem = blk - h * 320;
    const int b = rem / 5;
    const int s = rem - b * 5;
    const int tid = threadIdx.x;
    const int wv = tid >> 6, lane = tid & 63;
    const int quad = lane >> 4, l16 = lane & 15;

    // stage vw head slice (fp32 -> bf16), rows d=0..31 x 256c, pad 264
    {
        const int d = tid >> 3, c0 = (tid & 7) * 32;
        const float* src = vw + (size_t)(h * 32 + d) * C_ + c0;
        #pragma unroll
        for (int j = 0; j < 16; j++)
            *(int*)&vws[d * 264 + c0 + 2 * j] = pk_bf2(src[2 * j], src[2 * j + 1]);
    }
    // Q fragments (rows >=25 read finite garbage; those S-rows are discarded)
    short8 qf[2][8];
    {
        const unsigned short* qb = QT + (size_t)(b * H_ + h) * 25 * C_;
        #pragma unroll
        for (int mt = 0; mt < 2; mt++)
            #pragma unroll
            for (int ks = 0; ks < 8; ks++)
                qf[mt][ks] = *(const short8*)(qb + (mt * 16 + l16) * C_ + ks * 32 + quad * 8);
    }
    __syncthreads();
    short8 vwf[2][8];
    #pragma unroll
    for (int dt = 0; dt < 2; dt++)
        #pragma unroll
        for (int ks = 0; ks < 8; ks++)
            vwf[dt][ks] = *(const short8*)&vws[(dt * 16 + l16) * 264 + ks * 32 + quad * 8];

    floatx4 oc = {0.f, 0.f, 0.f, 0.f};
    float lsum[8];
    #pragma unroll
    for (int i = 0; i < 8; i++) lsum[i] = 0.f;
    const int mtv = wv & 1, dtv = wv >> 1;
    const unsigned short* xnc_b = XNC + ((size_t)(b * TV_ + s * 320)) * C_;

    for (int ti = 0; ti < 5; ti++) {
        const int par = ti & 1;
        floatx4 sc0 = {0.f,0.f,0.f,0.f}, sc1 = {0.f,0.f,0.f,0.f};
        floatx4 va0 = {0.f,0.f,0.f,0.f}, va1 = {0.f,0.f,0.f,0.f};
        {
            const unsigned short* xr = xnc_b + (size_t)(ti * 64 + wv * 16 + l16) * C_ + quad * 8;
            #pragma unroll
            for (int ks = 0; ks < 8; ks++) {
                const short8 bfv = *(const short8*)(xr + ks * 32);
                sc0 = __builtin_amdgcn_mfma_f32_16x16x32_bf16(qf[0][ks], bfv, sc0, 0, 0, 0);
                sc1 = __builtin_amdgcn_mfma_f32_16x16x32_bf16(qf[1][ks], bfv, sc1, 0, 0, 0);
                va0 = __builtin_amdgcn_mfma_f32_16x16x32_bf16(bfv, vwf[0][ks], va0, 0, 0, 0);
                va1 = __builtin_amdgcn_mfma_f32_16x16x32_bf16(bfv, vwf[1][ks], va1, 0, 0, 0);
            }
        }
        {
            const int colp = wv * 16 + l16;
            #pragma unroll
            for (int r = 0; r < 4; r++) {
                const float p0 = __builtin_amdgcn_exp2f(sc0[r]);
                const float p1 = __builtin_amdgcn_exp2f(sc1[r]);
                lsum[r] += p0;
                lsum[4 + r] += p1;
                P_s[par][(quad * 4 + r) * 72 + colp] = f2bf(p0);
                P_s[par][(16 + quad * 4 + r) * 72 + colp] = f2bf(p1);
                // V tile: row n = wv*16 + quad*4 + r, col d = dt*16 + l16
                V_s[par][l16 * 72 + wv * 16 + quad * 4 + r] = f2bf(va0[r]);
                V_s[par][(16 + l16) * 72 + wv * 16 + quad * 4 + r] = f2bf(va1[r]);
            }
        }
        __syncthreads();
        #pragma unroll
        for (int ks2 = 0; ks2 < 2; ks2++) {
            const short8 a  = *(const short8*)&P_s[par][(mtv * 16 + l16) * 72 + ks2 * 32 + quad * 8];
            const short8 bv = *(const short8*)&V_s[par][(dtv * 16 + l16) * 72 + ks2 * 32 + quad * 8];
            oc = __builtin_amdgcn_mfma_f32_16x16x32_bf16(a, bv, oc, 0, 0, 0);
        }
    }
    // lsum: sum over this wave's 16 columns (l16 dimension within each quad)
    #pragma unroll
    for (int i = 0; i < 8; i++) {
        float v = lsum[i];
        #pragma unroll
        for (int off = 1; off < 16; off <<= 1) v += __shfl_xor(v, off, 64);
        lsum[i] = v;
    }
    const size_t bh = (size_t)(b * H_ + h);
    if (l16 == 0) {
        #pragma unroll
        for (int mt = 0; mt < 2; mt++)
            #pragma unroll
            for (int r = 0; r < 4; r++) {
                const int q = mt * 16 + quad * 4 + r;
                if (q < 25) atomicAdd(&Lsum[bh * 32 + q], lsum[mt * 4 + r]);
            }
    }
    #pragma unroll
    for (int r = 0; r < 4; r++) {
        const int q = mtv * 16 + quad * 4 + r;
        if (q < 25)
            atomicAdd(&OA32[bh * 1024 + q * 32 + dtv * 16 + l16], oc[r]);
    }
}

// ---------------- K3: y[b,i,q] = pb[i] + sum_{h,d} pw[i,h*32+d] * OA32[b,h,q,d]/l[b,h,q] ------
__global__ __launch_bounds__(256) void k3_proj(const float* __restrict__ OA32,
        const float* __restrict__ Lsum, const float* __restrict__ pw,
        const float* __restrict__ pb, float* __restrict__ y) {
    __shared__ unsigned short pws[64 * 260];
    __shared__ unsigned short outs[28 * 264];   // rows 25..27 read-but-garbage, results discarded
    __shared__ float rl_s[256];
    __shared__ float ys[1600];
    const int blk = blockIdx.x;
    const int b = blk >> 2, i0 = (blk & 3) * 64;
    const int t = threadIdx.x;
    {
        const int hh = t >> 5, qq = t & 31;
        const float lv = Lsum[(size_t)(b * H_ + hh) * 32 + qq];
        rl_s[t] = (qq < 25) ? 1.0f / lv : 0.0f;
    }
    {
        const int ilw = t >> 2, seg = t & 3;
        const float* src = pw + (size_t)(i0 + ilw) * C_ + seg * 64;
        #pragma unroll
        for (int j = 0; j < 32; j++)
            *(int*)&pws[ilw * 260 + seg * 64 + 2 * j] = pk_bf2(src[2 * j], src[2 * j + 1]);
    }
    __syncthreads();
    {
        const float* src = OA32 + (size_t)b * (H_ * 1024);
        for (int k = t; k < V_ * C_; k += 256) {
            const int q = k >> 8, j = k & 255;
            const int hh = j >> 5, d = j & 31;
            outs[q * 264 + j] = f2bf(src[hh * 1024 + q * 32 + d] * rl_s[hh * 32 + q]);
        }
    }
    __syncthreads();
    const int il = t >> 2, qg = t & 3;
    const float bias = pb[i0 + il];
    float acc[7];
    #pragma unroll
    for (int jj = 0; jj < 7; jj++) acc[jj] = 0.f;
    for (int jv = 0; jv < 64; jv++) {
        const intx2 wp = *(const intx2*)&pws[il * 260 + 4 * jv];
        const float w0 = bf2f((unsigned short)(wp[0] & 0xffff));
        const float w1 = bf2f((unsigned short)((unsigned)wp[0] >> 16));
        const float w2 = bf2f((unsigned short)(wp[1] & 0xffff));
        const float w3 = bf2f((unsigned short)((unsigned)wp[1] >> 16));
        #pragma unroll
        for (int jj = 0; jj < 7; jj++) {
            const int q = qg + 4 * jj;
            const intx2 op = *(const intx2*)&outs[q * 264 + 4 * jv];
            const float o0 = bf2f((unsigned short)(op[0] & 0xffff));
            const float o1 = bf2f((unsigned short)((unsigned)op[0] >> 16));
            const float o2 = bf2f((unsigned short)(op[1] & 0xffff));
            const float o3 = bf2f((unsigned short)((unsigned)op[1] >> 16));
            acc[jj] += w0 * o0 + w1 * o1 + w2 * o2 + w3 * o3;
        }
    }
    #pragma unroll
    for (int jj = 0; jj < 7; jj++) {
        const int q = qg + 4 * jj;
        if (q < 25) ys[il * 25 + q] = bias + acc[jj];
    }
    __syncthreads();
    float* dst = y + (size_t)b * (C_ * V_) + i0 * 25;
    for (int k = t; k < 1600; k += 256) dst[k] = ys[k];
}

extern "C" void kernel_launch(void* const* d_in, const int* in_sizes, int n_in,
                              void* d_out, int out_size, void* d_ws, size_t ws_size,
                              hipStream_t stream) {
    const float* xcls = (const float*)d_in[0];
    const float* xp   = (const float*)d_in[1];
    const float* qw   = (const float*)d_in[2];
    const float* kw   = (const float*)d_in[3];
    const float* vw   = (const float*)d_in[4];
    const float* temp = (const float*)d_in[5];
    const float* pw   = (const float*)d_in[6];
    const float* pb   = (const float*)d_in[7];
    float* y = (float*)d_out;

    // ws: XNC bf16 52,428,800 | QT bf16 6,553,600 | OA32 f32 2,097,152 | L f32 65,536
    if (ws_size < (size_t)61145088) return;
    char* ws = (char*)d_ws;
    unsigned short* XNC  = (unsigned short*)ws;
    unsigned short* QT   = (unsigned short*)(ws + 52428800);
    float*          OA32 = (float*)(ws + 58982400);
    float*          L    = (float*)(ws + 61079552);

    hipLaunchKernelGGL(kz_zero,  dim3(528),  dim3(256), 0, stream, OA32);  // zeroes OA32+L
    hipLaunchKernelGGL(k1_trans, dim3(1600), dim3(256), 0, stream, xp, XNC);
    hipLaunchKernelGGL(k0_qtilde,dim3(512),  dim3(256), 0, stream, xcls, qw, kw, temp, QT);
    hipLaunchKernelGGL(k2_attn,  dim3(2560), dim3(256), 0, stream, XNC, QT, vw, OA32, L);
    hipLaunchKernelGGL(k3_proj,  dim3(256),  dim3(256), 0, stream, OA32, L, pw, pb, y);
}